// Round 2
// baseline (225.793 us; speedup 1.0000x reference)
//
#include <hip/hip_runtime.h>

// RNN_arch_2: 16-step vanilla RNN, B=16384, D_IN=64, D_H=256, D_MID=64, D_OUT=4.
// R4: kill the register spill. R2/R3 identical timing + VGPR_Count=128 +
// 17MB excess HBM writes showed the compiler spilled ~140 regs (the weight
// fragments, 192 regs) to scratch, chasing 4 waves/EU that the 2-block/CU
// grid can never use. amdgpu_waves_per_eu(2,2) pins the allocator at the
// 256-reg budget so weights genuinely persist in registers.
// Reg budget: wcat 160 + wof 32 + acc 40 + working ~30 => ~260 (minor cold
// spill at most). x_lds DMA dropped (LDS + addr regs); x loaded global->reg
// at step top, consumed at the END of the fused phase (h-slices first) so
// L2/L3 latency hides under 64 MFMAs.
// Structure kept from R3: h double-buffered in LDS -> 1 barrier/step; fused
// phase (pre-GEMM for h_{t+1} + h2o(h_t) share h fragments); swapped MFMA
// operands (W as A) -> ds_write_b64 epilogues; fc split-K over 256 threads,
// lagged 2 steps behind the barrier.

typedef _Float16 half8 __attribute__((ext_vector_type(8)));
typedef _Float16 half4 __attribute__((ext_vector_type(4)));
typedef float floatx4 __attribute__((ext_vector_type(4)));

#define T_STEPS  16
#define BATCH    16384
#define BLK_ROWS 32
#define HS       264   // h_lds row stride (f16): 528B -> 2-way bank alias, free
#define MS       72    // mid_lds row stride (f16)

__device__ inline float fast_tanh(float x) {
    // tanh(x) = 1 - 2/(1+exp2(2*log2e*x)); saturates correctly at +-inf
    float t = __builtin_amdgcn_exp2f(x * 2.8853900817779268f);
    return 1.0f - 2.0f * __builtin_amdgcn_rcpf(t + 1.0f);
}

__device__ inline half8 pack8(float4 a, float4 b) {
    half8 h;
    h[0] = (_Float16)a.x; h[1] = (_Float16)a.y; h[2] = (_Float16)a.z; h[3] = (_Float16)a.w;
    h[4] = (_Float16)b.x; h[5] = (_Float16)b.y; h[6] = (_Float16)b.z; h[7] = (_Float16)b.w;
    return h;
}

__device__ inline half8 cvt8(const float* __restrict__ p) {
    return pack8(((const float4*)p)[0], ((const float4*)p)[1]);
}

// Fused MFMA phase. Operand-swapped: mfma(a=W[idx][k], b=act[batch][k]) gives
// C[row = weight-dim (quad*4+r)][col = batch (l16)].
// h-slices first (LDS), x-slices last (afx loaded from global at step top,
// so its memory latency is covered by the 64-80 h-slice MFMAs).
template<int DO_PRE, int DO_MID>
__device__ __forceinline__ void mfma_phase(
    const _Float16* __restrict__ hcur, const half8 (&afx)[2][2],
    const half8 (&wcat)[10][4], const half8 (&wof)[8],
    floatx4 (&acc)[2][4], floatx4 (&ac2)[2], int l16, int quad)
{
    // h-part (K slices 2..9 of pre) + h2o share the same h fragments
    #pragma unroll
    for (int ks2 = 0; ks2 < 8; ++ks2) {
        half8 hf[2];
        #pragma unroll
        for (int mt = 0; mt < 2; ++mt)
            hf[mt] = *(const half8*)&hcur[(mt * 16 + l16) * HS + ks2 * 32 + quad * 8];
        if (DO_PRE) {
            #pragma unroll
            for (int mt = 0; mt < 2; ++mt)
                #pragma unroll
                for (int nt = 0; nt < 4; ++nt)
                    acc[mt][nt] = __builtin_amdgcn_mfma_f32_16x16x32_f16(
                        wcat[ks2 + 2][nt], hf[mt], acc[mt][nt], 0, 0, 0);
        }
        if (DO_MID) {
            #pragma unroll
            for (int mt = 0; mt < 2; ++mt)
                ac2[mt] = __builtin_amdgcn_mfma_f32_16x16x32_f16(
                    wof[ks2], hf[mt], ac2[mt], 0, 0, 0);
        }
    }
    // x-part (K slices 0..1)
    if (DO_PRE) {
        #pragma unroll
        for (int k2 = 0; k2 < 2; ++k2)
            #pragma unroll
            for (int mt = 0; mt < 2; ++mt)
                #pragma unroll
                for (int nt = 0; nt < 4; ++nt)
                    acc[mt][nt] = __builtin_amdgcn_mfma_f32_16x16x32_f16(
                        wcat[k2][nt], afx[mt][k2], acc[mt][nt], 0, 0, 0);
    }
}

// h = tanh(pre + bias) -> h_lds[nxt]; C row = hidden-dim -> 4 consecutive f16
__device__ __forceinline__ void epi_h(_Float16* __restrict__ hnxt,
                                      const floatx4 (&acc)[2][4],
                                      const float* __restrict__ biasPre,
                                      int w, int l16, int quad)
{
    #pragma unroll
    for (int nt = 0; nt < 4; ++nt) {
        int hb = w * 64 + nt * 16 + quad * 4;
        float4 bias = *(const float4*)&biasPre[hb];
        #pragma unroll
        for (int mt = 0; mt < 2; ++mt) {
            int mb = mt * 16 + l16;
            half4 v;
            v[0] = (_Float16)fast_tanh(acc[mt][nt][0] + bias.x);
            v[1] = (_Float16)fast_tanh(acc[mt][nt][1] + bias.y);
            v[2] = (_Float16)fast_tanh(acc[mt][nt][2] + bias.z);
            v[3] = (_Float16)fast_tanh(acc[mt][nt][3] + bias.w);
            *(half4*)&hnxt[mb * HS + hb] = v;
        }
    }
}

__device__ __forceinline__ void epi_mid(_Float16* __restrict__ midp,
                                        const floatx4 (&ac2)[2],
                                        const float* __restrict__ bo_lds,
                                        int w, int l16, int quad)
{
    int md = w * 16 + quad * 4;
    float4 bo4 = *(const float4*)&bo_lds[md];
    #pragma unroll
    for (int mt = 0; mt < 2; ++mt) {
        int mb = mt * 16 + l16;
        half4 v;
        v[0] = (_Float16)fast_tanh(ac2[mt][0] + bo4.x);
        v[1] = (_Float16)fast_tanh(ac2[mt][1] + bo4.y);
        v[2] = (_Float16)fast_tanh(ac2[mt][2] + bo4.z);
        v[3] = (_Float16)fast_tanh(ac2[mt][3] + bo4.w);
        *(half4*)&midp[mb * MS + md] = v;
    }
}

// out = mid @ Wfc^T + bfc : 256 threads, split-K pairs combined via shfl_xor
__device__ __forceinline__ void fc_out(const _Float16* __restrict__ midp,
                                       const _Float16* __restrict__ wfc,
                                       const float* __restrict__ bfc,
                                       float* __restrict__ outp,
                                       int ti, int b0, int tid)
{
    const int row = tid >> 3, oc = (tid >> 1) & 3, kh = tid & 1;
    float s = 0.f;
    #pragma unroll
    for (int k8 = 0; k8 < 32; k8 += 8) {
        half8 mv = *(const half8*)&midp[row * MS + kh * 32 + k8];
        half8 wv = *(const half8*)&wfc[oc * 64 + kh * 32 + k8];
        #pragma unroll
        for (int j = 0; j < 8; ++j) s += (float)mv[j] * (float)wv[j];
    }
    s += __shfl_xor(s, 1, 64);
    if (kh == 0)
        outp[((size_t)ti * BATCH + b0 + row) * 4 + oc] = s + bfc[oc];
}

__global__ __launch_bounds__(256)
__attribute__((amdgpu_waves_per_eu(2, 2)))
void rnn_kernel(
    const float* __restrict__ x,   const float* __restrict__ hc1,
    const float* __restrict__ Wi,  const float* __restrict__ bi,
    const float* __restrict__ Wh,  const float* __restrict__ bh,
    const float* __restrict__ Wo,  const float* __restrict__ bo,
    const float* __restrict__ Wf,  const float* __restrict__ bf,
    float* __restrict__ out)
{
    __shared__ _Float16 h_lds[2][BLK_ROWS * HS];    // double-buffered h (f16)
    __shared__ _Float16 mid_lds[2][BLK_ROWS * MS];  // double-buffered mid
    __shared__ float    biasPre[256];               // b_i2h + b_h2h
    __shared__ float    bo_lds[64];
    __shared__ _Float16 wfc_lds[4 * 64];
    __shared__ float    bfc_lds[4];

    const int tid  = threadIdx.x;
    const int w    = tid >> 6;
    const int lane = tid & 63;
    const int l16  = lane & 15;
    const int quad = lane >> 4;
    const int b0   = blockIdx.x * BLK_ROWS;

#define LOAD_AFX(ti) do {                                                          \
        _Pragma("unroll")                                                          \
        for (int mt = 0; mt < 2; ++mt) {                                           \
            const float* xr_ = x + ((size_t)(ti) * BATCH + b0 + mt * 16 + l16) * 64;\
            _Pragma("unroll")                                                      \
            for (int k2 = 0; k2 < 2; ++k2)                                         \
                afx[mt][k2] = cvt8(xr_ + k2 * 32 + quad * 8);                      \
        }                                                                          \
    } while (0)

#define ZERO_ACC() do {                                                                \
        _Pragma("unroll")                                                              \
        for (int mt = 0; mt < 2; ++mt) {                                               \
            ac2[mt] = (floatx4){0.f, 0.f, 0.f, 0.f};                                   \
            _Pragma("unroll")                                                          \
            for (int nt = 0; nt < 4; ++nt) acc[mt][nt] = (floatx4){0.f, 0.f, 0.f, 0.f};\
        }                                                                              \
    } while (0)

    // --- one-time LDS init ---
    biasPre[tid] = bi[tid] + bh[tid];
    if (tid < 64) bo_lds[tid] = bo[tid];
    wfc_lds[tid] = (_Float16)Wf[tid];
    if (tid < 4) bfc_lds[tid] = bf[tid];

    // stage hc1 -> h_lds[0]
    {
        const int r = tid >> 3, c0 = (tid & 7) * 32;
        const float4* src = (const float4*)&hc1[(size_t)(b0 + r) * 256 + c0];
        #pragma unroll
        for (int i2 = 0; i2 < 8; ++i2) {
            float4 v = src[i2];
            half4 hv;
            hv[0] = (_Float16)v.x; hv[1] = (_Float16)v.y;
            hv[2] = (_Float16)v.z; hv[3] = (_Float16)v.w;
            *(half4*)&h_lds[0][r * HS + c0 + i2 * 4] = hv;
        }
    }

    // --- persistent weight fragments (registers, loaded once) ---
    half8 wcat[10][4];   // K=320 concat [Wi(k<64); Wh], 4 n-tiles/wave
    #pragma unroll
    for (int ks = 0; ks < 10; ++ks)
        #pragma unroll
        for (int nt = 0; nt < 4; ++nt) {
            int j = w * 64 + nt * 16 + l16;
            const float* src = (ks < 2)
                ? (Wi + (size_t)j * 64  + ks * 32 + quad * 8)
                : (Wh + (size_t)j * 256 + (ks - 2) * 32 + quad * 8);
            wcat[ks][nt] = cvt8(src);
        }
    half8 wof[8];        // W_h2o: wave covers 16 mid-dims, K=256
    #pragma unroll
    for (int ks = 0; ks < 8; ++ks)
        wof[ks] = cvt8(Wo + (size_t)(w * 16 + l16) * 256 + ks * 32 + quad * 8);

    __syncthreads();

    // ---- i = 0 : pre only ----
    {
        half8 afx[2][2];
        LOAD_AFX(0);
        floatx4 acc[2][4], ac2[2];
        ZERO_ACC();
        mfma_phase<1, 0>(h_lds[0], afx, wcat, wof, acc, ac2, l16, quad);
        epi_h(h_lds[1], acc, biasPre, w, l16, quad);
        __syncthreads();
    }

    // ---- main loop: i = 1..15, ONE barrier each ----
    #pragma unroll 1
    for (int i = 1; i <= 15; ++i) {
        const int cur = i & 1, nxt = cur ^ 1;
        half8 afx[2][2];
        LOAD_AFX(i);                     // issued first: latency hides under h-MFMAs
        if (i >= 2) fc_out(mid_lds[nxt], wfc_lds, bfc_lds, out, i - 2, b0, tid);
        floatx4 acc[2][4], ac2[2];
        ZERO_ACC();
        mfma_phase<1, 1>(h_lds[cur], afx, wcat, wof, acc, ac2, l16, quad);
        epi_h(h_lds[nxt], acc, biasPre, w, l16, quad);
        epi_mid(mid_lds[cur], ac2, bo_lds, w, l16, quad);
        __syncthreads();
    }

    // ---- i = 16 : h2o(h_16) + drain fc ----
    {
        fc_out(mid_lds[1], wfc_lds, bfc_lds, out, 14, b0, tid);
        half8 afx[2][2];   // unused by phase<0,1>
        floatx4 acc[2][4], ac2[2];
        ZERO_ACC();
        mfma_phase<0, 1>(h_lds[0], afx, wcat, wof, acc, ac2, l16, quad);
        epi_mid(mid_lds[0], ac2, bo_lds, w, l16, quad);
        __syncthreads();
        fc_out(mid_lds[0], wfc_lds, bfc_lds, out, 15, b0, tid);
    }

    // ---- h_final (fp32) at offset T*B*4, from h_lds[0] ----
    {
        const int r = tid >> 3, c0 = (tid & 7) * 32;
        float4* dst = (float4*)&out[(size_t)T_STEPS * BATCH * 4 + (size_t)(b0 + r) * 256 + c0];
        #pragma unroll
        for (int i2 = 0; i2 < 8; ++i2) {
            int c = c0 + i2 * 4;
            float4 v;
            v.x = (float)h_lds[0][r * HS + c + 0];
            v.y = (float)h_lds[0][r * HS + c + 1];
            v.z = (float)h_lds[0][r * HS + c + 2];
            v.w = (float)h_lds[0][r * HS + c + 3];
            dst[i2] = v;
        }
    }
#undef LOAD_AFX
#undef ZERO_ACC
}

extern "C" void kernel_launch(void* const* d_in, const int* in_sizes, int n_in,
                              void* d_out, int out_size, void* d_ws, size_t ws_size,
                              hipStream_t stream) {
    const float* x   = (const float*)d_in[0];
    const float* hc1 = (const float*)d_in[1];
    const float* Wi  = (const float*)d_in[2];
    const float* bi  = (const float*)d_in[3];
    const float* Wh  = (const float*)d_in[4];
    const float* bh  = (const float*)d_in[5];
    const float* Wo  = (const float*)d_in[6];
    const float* bo  = (const float*)d_in[7];
    const float* Wf  = (const float*)d_in[8];
    const float* bf  = (const float*)d_in[9];

    rnn_kernel<<<BATCH / BLK_ROWS, 256, 0, stream>>>(
        x, hc1, Wi, bi, Wh, bh, Wo, bo, Wf, bf, (float*)d_out);
}